// Round 3
// baseline (276.876 us; speedup 1.0000x reference)
//
#include <hip/hip_runtime.h>

// VanillaRNN: B=4096, T=1024, I=3, H=32, O=2
// out[b,t,j] = h_t[j];  h_t = tanh(x_t @ W_ih^T + b_ih + b_hh + h_{t-1} @ W_hh^T)
// h_n[b,o] = h_T @ W_fc^T + b_fc
//
// R3: recurrence chain is register-only. h exchange via
//   - ds_swizzle xor16 (other 16-row's h), latency hidden under tanh tail
//   - chained DPP row_ror:1 on both h regs (15 rotations), pure VALU
// W_hh preloaded per-lane in rotation order as float2 pairs -> v_pk_fma_f32.
// LDS used only for the tiny h_n epilogue.

typedef float f2 __attribute__((ext_vector_type(2)));

#define RNN_B 4096
#define RNN_T 1024
#define RNN_H 32
#define GROUPS 8              // batch elements per block
#define BLOCK (GROUPS * 32)   // 256 threads
#define DEPTH 4               // T-unroll / x prefetch distance

__device__ __forceinline__ float rot_ror1(float v) {
    // DPP row_ror:1  (ctrl 0x120+n): lane i reads lane (i-1)&15 of its 16-row
    return __int_as_float(__builtin_amdgcn_mov_dpp(__float_as_int(v), 0x121, 0xf, 0xf, true));
}

__global__ __launch_bounds__(BLOCK) void vanilla_rnn_kernel(
    const float* __restrict__ x,     // [B,T,3]
    const float* __restrict__ W_ih,  // [32,3]
    const float* __restrict__ b_ih,  // [32]
    const float* __restrict__ W_hh,  // [32,32]
    const float* __restrict__ b_hh,  // [32]
    const float* __restrict__ W_fc,  // [2,32]
    const float* __restrict__ b_fc,  // [2]
    float* __restrict__ out,         // [B,T,32]
    float* __restrict__ hn_out)      // [B,2]
{
    const int tid = threadIdx.x;
    const int g   = tid >> 5;        // batch within block
    const int j   = tid & 31;        // output index within H
    const int p   = j & 15;          // position within 16-row
    const int hi  = j >> 4;          // which 16-row half
    const int b   = blockIdx.x * GROUPS + g;

    __shared__ float hs[GROUPS][32]; // epilogue only

    // W_hh row j, in DPP-rotation order, paired (own-half k, other-half k).
    // After m chained row_ror:1 steps, own-reg holds h[ka(m)], swz-reg h[kb(m)].
    f2 Wp[16];
#pragma unroll
    for (int m = 0; m < 16; ++m) {
        const int ka = ((p - m) & 15) | (hi << 4);
        const int kb = ((p - m) & 15) | ((hi ^ 1) << 4);
        Wp[m].x = W_hh[j * 32 + ka];
        Wp[m].y = W_hh[j * 32 + kb];
    }

    const float wi0 = W_ih[j * 3 + 0];
    const float wi1 = W_ih[j * 3 + 1];
    const float wi2 = W_ih[j * 3 + 2];
    const float bsum = b_ih[j] + b_hh[j];

    const float* xb = x + (size_t)b * RNN_T * 3;
    float*       ob = out + (size_t)b * RNN_T * RNN_H;

    // x prefetch buffer: one full unroll block ahead
    float xs[DEPTH][3];
#pragma unroll
    for (int d = 0; d < DEPTH; ++d)
#pragma unroll
        for (int c = 0; c < 3; ++c) xs[d][c] = xb[d * 3 + c];

    float hj = 0.0f;                 // h[j], register-resident state

    for (int tb = 0; tb < RNN_T; tb += DEPTH) {
        const int tnb = (tb + DEPTH < RNN_T) ? (tb + DEPTH) : tb;
        float nxs[DEPTH][3];
#pragma unroll
        for (int d = 0; d < DEPTH; ++d)
#pragma unroll
            for (int c = 0; c < 3; ++c) nxs[d][c] = xb[(tnb + d) * 3 + c];

#pragma unroll
        for (int d = 0; d < DEPTH; ++d) {
            // other 16-row's h via xor-16 swizzle (within each 32-lane group)
            const float swv = __int_as_float(
                __builtin_amdgcn_ds_swizzle(__float_as_int(hj), 0x401f));

            f2 acc;
            acc.x = bsum + wi0 * xs[d][0] + wi1 * xs[d][1] + wi2 * xs[d][2];
            acc.y = 0.0f;

            f2 hp;
            hp.x = hj;
            hp.y = swv;
            acc = __builtin_elementwise_fma(hp, Wp[0], acc);
#pragma unroll
            for (int m = 1; m < 16; ++m) {
                hp.x = rot_ror1(hp.x);
                hp.y = rot_ror1(hp.y);
                acc = __builtin_elementwise_fma(hp, Wp[m], acc);
            }
            const float y = acc.x + acc.y;

            // tanh(y) = 1 - 2/(exp(2y)+1); rcp approx, inf-safe
            const float e  = __expf(2.0f * y);
            const float th = fmaf(-2.0f, __builtin_amdgcn_rcpf(e + 1.0f), 1.0f);

            __builtin_nontemporal_store(th, &ob[(tb + d) * RNN_H + j]);
            hj = th;
        }

#pragma unroll
        for (int d = 0; d < DEPTH; ++d)
#pragma unroll
            for (int c = 0; c < 3; ++c) xs[d][c] = nxs[d][c];
    }

    // h_n = h_T @ W_fc^T + b_fc  (wave-internal, no barrier)
    hs[g][j] = hj;
    if (j < 2) {
        float acc = b_fc[j];
#pragma unroll
        for (int k = 0; k < 32; ++k) acc = fmaf(W_fc[j * 32 + k], hs[g][k], acc);
        hn_out[(size_t)b * 2 + j] = acc;
    }
}

extern "C" void kernel_launch(void* const* d_in, const int* in_sizes, int n_in,
                              void* d_out, int out_size, void* d_ws, size_t ws_size,
                              hipStream_t stream) {
    const float* x    = (const float*)d_in[0];
    const float* W_ih = (const float*)d_in[1];
    const float* b_ih = (const float*)d_in[2];
    const float* W_hh = (const float*)d_in[3];
    const float* b_hh = (const float*)d_in[4];
    const float* W_fc = (const float*)d_in[5];
    const float* b_fc = (const float*)d_in[6];

    float* out    = (float*)d_out;                                   // [B,T,H]
    float* hn_out = out + (size_t)RNN_B * RNN_T * RNN_H;             // [B,2]

    const int grid = RNN_B / GROUPS;  // 512 blocks
    vanilla_rnn_kernel<<<grid, BLOCK, 0, stream>>>(
        x, W_ih, b_ih, W_hh, b_hh, W_fc, b_fc, out, hn_out);
}

// Round 5
// 223.821 us; speedup vs baseline: 1.2370x; 1.2370x over previous
//
#include <hip/hip_runtime.h>

// VanillaRNN: B=4096, T=1024, I=3, H=32, O=2
// out[b,t,j] = h_t[j];  h_t = tanh(x_t @ W_ih^T + b_ih + b_hh + h_{t-1} @ W_hh^T)
// h_n[b,o] = h_T @ W_fc^T + b_fc
//
// R4b: zero LDS in the recurrence. Lane p of a 16-lane group owns outputs
// j=2p,2p+1; state pair (h[2p],h[2p+1]) in 2 VGPRs. All 32 h's reached via
// INDEPENDENT dpp row_ror:m (m=1..15) from the original pair (not a chain).
// W_hh rows pre-scaled by 2*log2(e): tanh = 1 - 2*rcp(exp2(y')+1).
// 4 batches/wave, 1024 waves (1/SIMD) -> short-chain latency design.
// (R4 -> R4b: nontemporal store through ext-vector f2, not HIP float2.)

typedef float f2 __attribute__((ext_vector_type(2)));

#define RNN_B 4096
#define RNN_T 1024
#define RNN_H 32
#define GROUPS 16             // batches per block (16-lane groups)
#define BLOCK 256
#define DEPTH 4               // T-unroll / x prefetch distance

#define SCALE 2.8853900817779268f   // 2*log2(e)

template <int M>
__device__ __forceinline__ f2 rotm(f2 v) {
    // DPP row_ror:M — lane i reads lane (i-M)&15 within its 16-lane row
    f2 r;
    r.x = __int_as_float(__builtin_amdgcn_mov_dpp(__float_as_int(v.x), 0x120 | M, 0xf, 0xf, true));
    r.y = __int_as_float(__builtin_amdgcn_mov_dpp(__float_as_int(v.y), 0x120 | M, 0xf, 0xf, true));
    return r;
}

__global__ __launch_bounds__(BLOCK) void vanilla_rnn_kernel(
    const float* __restrict__ x,     // [B,T,3]
    const float* __restrict__ W_ih,  // [32,3]
    const float* __restrict__ b_ih,  // [32]
    const float* __restrict__ W_hh,  // [32,32]
    const float* __restrict__ b_hh,  // [32]
    const float* __restrict__ W_fc,  // [2,32]
    const float* __restrict__ b_fc,  // [2]
    float* __restrict__ out,         // [B,T,32]
    float* __restrict__ hn_out)      // [B,2]
{
    const int tid = threadIdx.x;
    const int g   = tid >> 4;        // batch group within block
    const int p   = tid & 15;        // pair position within 16-lane row
    const int b   = blockIdx.x * GROUPS + g;
    const int j0  = 2 * p;
    const int j1  = 2 * p + 1;

    __shared__ float hs[GROUPS][32]; // epilogue only

    // W_hh rows j0,j1 in rotation order (pair q=(p-m)&15), pre-scaled.
    f2 Wa[16], Wb[16];
#pragma unroll
    for (int m = 0; m < 16; ++m) {
        const int q = (p - m) & 15;
        Wa[m].x = W_hh[j0 * 32 + 2 * q]     * SCALE;
        Wa[m].y = W_hh[j0 * 32 + 2 * q + 1] * SCALE;
        Wb[m].x = W_hh[j1 * 32 + 2 * q]     * SCALE;
        Wb[m].y = W_hh[j1 * 32 + 2 * q + 1] * SCALE;
    }

    // x-projection constants for both owned outputs (.x -> j0, .y -> j1)
    f2 wi0, wi1, wi2, bs;
    wi0.x = W_ih[j0 * 3 + 0] * SCALE;  wi0.y = W_ih[j1 * 3 + 0] * SCALE;
    wi1.x = W_ih[j0 * 3 + 1] * SCALE;  wi1.y = W_ih[j1 * 3 + 1] * SCALE;
    wi2.x = W_ih[j0 * 3 + 2] * SCALE;  wi2.y = W_ih[j1 * 3 + 2] * SCALE;
    bs.x  = (b_ih[j0] + b_hh[j0]) * SCALE;
    bs.y  = (b_ih[j1] + b_hh[j1]) * SCALE;

    const float* xb = x + (size_t)b * RNN_T * 3;
    float*       ob = out + (size_t)b * RNN_T * RNN_H;

    float xs[DEPTH][3];
#pragma unroll
    for (int d = 0; d < DEPTH; ++d)
#pragma unroll
        for (int c = 0; c < 3; ++c) xs[d][c] = xb[d * 3 + c];

    float hj0 = 0.0f, hj1 = 0.0f;

    for (int tb = 0; tb < RNN_T; tb += DEPTH) {
        const int tnb = (tb + DEPTH < RNN_T) ? (tb + DEPTH) : tb;
        float nxs[DEPTH][3];
#pragma unroll
        for (int d = 0; d < DEPTH; ++d)
#pragma unroll
            for (int c = 0; c < 3; ++c) nxs[d][c] = xb[(tnb + d) * 3 + c];

        // pre-scaled x-projection for this block (h-independent)
        f2 xp[DEPTH];
#pragma unroll
        for (int d = 0; d < DEPTH; ++d) {
            f2 v = bs;
            v = __builtin_elementwise_fma(wi0, (f2){xs[d][0], xs[d][0]}, v);
            v = __builtin_elementwise_fma(wi1, (f2){xs[d][1], xs[d][1]}, v);
            v = __builtin_elementwise_fma(wi2, (f2){xs[d][2], xs[d][2]}, v);
            xp[d] = v;
        }

#pragma unroll
        for (int d = 0; d < DEPTH; ++d) {
            f2 hp; hp.x = hj0; hp.y = hj1;

            f2 acc_a, acc_b;
            acc_a.x = xp[d].x; acc_a.y = 0.0f;
            acc_b.x = xp[d].y; acc_b.y = 0.0f;

            acc_a = __builtin_elementwise_fma(hp, Wa[0], acc_a);
            acc_b = __builtin_elementwise_fma(hp, Wb[0], acc_b);
#define ROT_STEP(M)                                              \
            {                                                    \
                const f2 r = rotm<M>(hp);                        \
                acc_a = __builtin_elementwise_fma(r, Wa[M], acc_a); \
                acc_b = __builtin_elementwise_fma(r, Wb[M], acc_b); \
            }
            ROT_STEP(1)  ROT_STEP(2)  ROT_STEP(3)  ROT_STEP(4)
            ROT_STEP(5)  ROT_STEP(6)  ROT_STEP(7)  ROT_STEP(8)
            ROT_STEP(9)  ROT_STEP(10) ROT_STEP(11) ROT_STEP(12)
            ROT_STEP(13) ROT_STEP(14) ROT_STEP(15)
#undef ROT_STEP

            const float ya = acc_a.x + acc_a.y;   // = 2*log2e * (pre-tanh)
            const float yb = acc_b.x + acc_b.y;

            // tanh(z) = 1 - 2/(exp2(2*log2e*z)+1); inf-safe
            const float ea = exp2f(ya);
            const float eb = exp2f(yb);
            const float tha = fmaf(-2.0f, __builtin_amdgcn_rcpf(ea + 1.0f), 1.0f);
            const float thb = fmaf(-2.0f, __builtin_amdgcn_rcpf(eb + 1.0f), 1.0f);

            f2 st; st.x = tha; st.y = thb;
            __builtin_nontemporal_store(
                st, reinterpret_cast<f2*>(ob + (size_t)(tb + d) * RNN_H) + p);

            hj0 = tha; hj1 = thb;
        }

#pragma unroll
        for (int d = 0; d < DEPTH; ++d)
#pragma unroll
            for (int c = 0; c < 3; ++c) xs[d][c] = nxs[d][c];
    }

    // h_n = h_T @ W_fc^T + b_fc  (16-lane group is wave-internal, no barrier)
    hs[g][j0] = hj0;
    hs[g][j1] = hj1;
    if (p < 2) {
        float acc = b_fc[p];
#pragma unroll
        for (int k = 0; k < 32; ++k) acc = fmaf(W_fc[p * 32 + k], hs[g][k], acc);
        hn_out[(size_t)b * 2 + p] = acc;
    }
}

extern "C" void kernel_launch(void* const* d_in, const int* in_sizes, int n_in,
                              void* d_out, int out_size, void* d_ws, size_t ws_size,
                              hipStream_t stream) {
    const float* x    = (const float*)d_in[0];
    const float* W_ih = (const float*)d_in[1];
    const float* b_ih = (const float*)d_in[2];
    const float* W_hh = (const float*)d_in[3];
    const float* b_hh = (const float*)d_in[4];
    const float* W_fc = (const float*)d_in[5];
    const float* b_fc = (const float*)d_in[6];

    float* out    = (float*)d_out;                                   // [B,T,H]
    float* hn_out = out + (size_t)RNN_B * RNN_T * RNN_H;             // [B,2]

    const int grid = RNN_B / GROUPS;  // 256 blocks
    vanilla_rnn_kernel<<<grid, BLOCK, 0, stream>>>(
        x, W_ih, b_ih, W_hh, b_hh, W_fc, b_fc, out, hn_out);
}